// Round 1
// baseline (136.309 us; speedup 1.0000x reference)
//
#include <hip/hip_runtime.h>
#include <math.h>

#define T_  1024
#define S_  64
#define D_  256
#define TP_ 8
#define H_  16
#define C_  65
#define CUR_TP_ 4

__device__ __forceinline__ float cos_sim_i(int a, int b) {
    float sg = ((a >= 0) == (b >= 0)) ? 1.0f : -1.0f;
    int aa = a < 0 ? -a : a;
    int bb = b < 0 ? -b : b;
    int x = (aa ^ bb) + 1;          // >= 1, <= 2^17
    int e = 32 - __clz(x);          // == frexp exponent for integer x
    return sg * (1.0f - (float)e * 0.0625f);
}

// cnc_loc[t,c,p] from sta_loc value sl and this t's rand_numbers row (h*16+k*8+p)
__device__ __forceinline__ int cnc_val(int c, int sl, const int* rn_row, int p) {
    if (c == 32) return sl;
    int cc = (c < 32) ? c : (c - 33);
    int h = cc >> 1, k = cc & 1;
    int m = rn_row[h * 16 + k * 8 + p] & ((1 << h) - 1);
    int v = (sl ^ (1 << h)) ^ m;
    return (c < 32) ? v : -v;
}

__global__ __launch_bounds__(256) void critigraph_kernel(
    const int* __restrict__ sta_loc,      // (T, TP)
    const int* __restrict__ nei_loc,      // (T, S, TP)
    const int* __restrict__ rand_numbers, // (T, H, 2, TP)
    const float* __restrict__ sta_emb,    // (T, D)
    const float* __restrict__ nei_emb,    // (T, S, D)
    const float* __restrict__ mask,       // (T, S)
    const float* __restrict__ rand_vals,  // (T, TP)
    const float* __restrict__ t_rand,     // (T,)
    float* __restrict__ out_sel,          // (T, TP) selected_locs as float
    float* __restrict__ out_loss)         // (T,)   real_loss
{
    const int t = blockIdx.x;
    const int tid = threadIdx.x;
    const int lane = tid & 63;
    const int wave = tid >> 6;

    __shared__ __align__(16) float s_sta[D_];
    __shared__ int   s_nl[S_ * TP_];
    __shared__ int   s_rn[H_ * 2 * TP_];
    __shared__ int   s_sl[TP_];
    __shared__ float s_m[S_];
    __shared__ float s_eu[S_];
    __shared__ float s_w[S_];
    __shared__ float s_cs[S_ * TP_];
    __shared__ float s_css[S_];
    __shared__ float s_loss[C_ * TP_];
    __shared__ float s_red[4];
    __shared__ float s_inv;
    __shared__ float s_lth;
    __shared__ int   s_cidx[TP_];

    // ---- stage per-t data ----
    s_sta[tid] = sta_emb[t * D_ + tid];
    s_nl[tid]       = nei_loc[t * S_ * TP_ + tid];
    s_nl[tid + 256] = nei_loc[t * S_ * TP_ + tid + 256];
    s_rn[tid] = rand_numbers[t * 256 + tid];
    if (tid < TP_) s_sl[tid] = sta_loc[t * TP_ + tid];
    if (tid < S_)  s_m[tid]  = mask[t * S_ + tid];
    __syncthreads();

    // ---- sta inv-norm ----
    {
        float v = s_sta[tid];
        float sq = v * v;
        for (int off = 32; off; off >>= 1) sq += __shfl_xor(sq, off, 64);
        if (lane == 0) s_red[wave] = sq;
    }
    __syncthreads();
    if (tid == 0) {
        float tot = s_red[0] + s_red[1] + s_red[2] + s_red[3];
        s_inv = 1.0f / sqrtf(tot);
        float c = 0.f;
        for (int s = 0; s < S_; s++) c += s_m[s];
        s_lth = c + 1e-12f;
    }
    __syncthreads();

    // ---- eu per s (wave-parallel dot, coalesced float4) ----
    {
        float4 sv = reinterpret_cast<const float4*>(s_sta)[lane];
        const float4* nrow = reinterpret_cast<const float4*>(nei_emb + (size_t)t * S_ * D_);
        for (int i = 0; i < 16; i++) {
            int s = wave * 16 + i;
            float4 nv = nrow[s * (D_ / 4) + lane];
            float d0 = nv.x * sv.x + nv.y * sv.y + nv.z * sv.z + nv.w * sv.w;
            float n0 = nv.x * nv.x + nv.y * nv.y + nv.z * nv.z + nv.w * nv.w;
            for (int off = 32; off; off >>= 1) {
                d0 += __shfl_xor(d0, off, 64);
                n0 += __shfl_xor(n0, off, 64);
            }
            if (lane == 0) {
                float eu = d0 * s_inv * (1.0f / sqrtf(n0));
                s_eu[s] = eu;
                s_w[s]  = fabsf(eu) * s_m[s];
            }
        }
    }

    // ---- cos_sn (independent of eu, no barrier needed before) ----
    for (int q = tid; q < S_ * TP_; q += 256) {
        int p = q & 7;
        s_cs[q] = cos_sim_i(s_sl[p], s_nl[q]);
    }
    __syncthreads();
    if (tid < S_) {
        float a = 0.f;
        for (int p = 0; p < TP_; p++) a += s_cs[tid * 8 + p];
        s_css[tid] = a;   // exact: multiples of 1/16
    }
    __syncthreads();

    // ---- loss[c][p] = sum_s ((css[s]-cs[s,p]+cos_cn)/8 - eu[s])^2 * (|eu|*mask) / lth ----
    for (int q = tid; q < C_ * TP_; q += 256) {
        int c = q >> 3, p = q & 7;
        int v = cnc_val(c, s_sl[p], s_rn, p);
        float acc = 0.f;
        for (int s = 0; s < S_; s++) {
            float cc = cos_sim_i(v, s_nl[s * 8 + p]);
            float ct = (s_css[s] - s_cs[s * 8 + p] + cc) * 0.125f;  // exact numerator
            float d = ct - s_eu[s];
            acc += d * d * s_w[s];
        }
        s_loss[q] = acc / s_lth;
    }
    __syncthreads();

    // ---- argmin over c per p (first-min tie-break, ascending scan) ----
    if (tid < TP_) {
        float best = s_loss[tid];
        int bi = 0;
        for (int c = 1; c < C_; c++) {
            float v = s_loss[c * 8 + tid];
            if (v < best) { best = v; bi = c; }
        }
        s_cidx[tid] = bi;   // temp: argmin_all
    }
    __syncthreads();

    // ---- selection: 4 smallest rand_vals (stable), t_rand gate ----
    if (tid == 0) {
        float rv[TP_];
        int am[TP_], cidx[TP_];
        bool taken[TP_];
        for (int p = 0; p < TP_; p++) {
            rv[p] = rand_vals[t * TP_ + p];
            am[p] = s_cidx[p];
            cidx[p] = 32;
            taken[p] = false;
        }
        bool sel = t_rand[t] < 0.8f;
        for (int j = 0; j < CUR_TP_; j++) {
            int bi = -1; float bv = 0.f;
            for (int p = 0; p < TP_; p++) {
                if (taken[p]) continue;
                if (bi < 0 || rv[p] < bv) { bi = p; bv = rv[p]; }  // strict <: stable
            }
            taken[bi] = true;
            cidx[bi] = sel ? am[bi] : 32;
        }
        for (int p = 0; p < TP_; p++) s_cidx[p] = cidx[p];
    }
    __syncthreads();

    // ---- outputs ----
    if (tid < TP_) {
        int c = s_cidx[tid];
        int v = cnc_val(c, s_sl[tid], s_rn, tid);
        out_sel[t * TP_ + tid] = (float)v;
    }
    if (tid == 64) {
        float a = 0.f;
        for (int p = 0; p < TP_; p++) a += s_loss[s_cidx[p] * 8 + p];
        out_loss[t] = a * 0.125f;   // mean over TP (exact /8)
    }
}

extern "C" void kernel_launch(void* const* d_in, const int* in_sizes, int n_in,
                              void* d_out, int out_size, void* d_ws, size_t ws_size,
                              hipStream_t stream) {
    const int*   sta_loc      = (const int*)d_in[0];
    const int*   nei_loc      = (const int*)d_in[1];
    const int*   rand_numbers = (const int*)d_in[2];
    const float* sta_emb      = (const float*)d_in[3];
    const float* nei_emb      = (const float*)d_in[4];
    const float* mask         = (const float*)d_in[5];
    const float* rand_vals    = (const float*)d_in[6];
    const float* t_rand       = (const float*)d_in[7];

    float* out_sel  = (float*)d_out;
    float* out_loss = out_sel + T_ * TP_;

    critigraph_kernel<<<T_, 256, 0, stream>>>(
        sta_loc, nei_loc, rand_numbers, sta_emb, nei_emb, mask,
        rand_vals, t_rand, out_sel, out_loss);
}

// Round 3
// 113.424 us; speedup vs baseline: 1.2018x; 1.2018x over previous
//
#include <hip/hip_runtime.h>
#include <math.h>

#define T_  1024
#define S_  64
#define D_  256
#define TP_ 8
#define C_  65

__device__ __forceinline__ int cnc_val(int c, int sl, const int* rn_row, int p) {
    if (c == 32) return sl;
    int cc = (c < 32) ? c : (c - 33);
    int h = cc >> 1, k = cc & 1;
    int m = rn_row[h * 16 + k * 8 + p] & ((1 << h) - 1);
    int v = (sl ^ (1 << h)) ^ m;
    return (c < 32) ? v : -v;
}

__device__ __forceinline__ float cos_sim_i(int a, int b) {
    float sg = ((a >= 0) == (b >= 0)) ? 1.0f : -1.0f;
    int aa = a < 0 ? -a : a;
    int bb = b < 0 ? -b : b;
    int x = (aa ^ bb) + 1;
    int e = 32 - __clz(x);
    return sg * (1.0f - (float)e * 0.0625f);
}

__global__ __launch_bounds__(256, 4) void critigraph_kernel(
    const int* __restrict__ sta_loc,      // (T, 8)
    const int* __restrict__ nei_loc,      // (T, 64, 8)
    const int* __restrict__ rand_numbers, // (T, 16, 2, 8)
    const float* __restrict__ sta_emb,    // (T, 256)
    const float* __restrict__ nei_emb,    // (T, 64, 256)
    const float* __restrict__ mask,       // (T, 64)
    const float* __restrict__ rand_vals,  // (T, 8)
    const float* __restrict__ t_rand,     // (T,)
    float* __restrict__ out_sel,          // (T, 8)
    float* __restrict__ out_loss)         // (T,)
{
    const int t = blockIdx.x;
    const int tid = threadIdx.x;
    const int lane = tid & 63;
    const int wave = tid >> 6;

    __shared__ __align__(16) float s_sta[D_];
    __shared__ __align__(16) float4 s_cb[512];   // (sign|abs(nl), css-cs, eu, w)
    __shared__ int   s_nl[512];
    __shared__ int   s_rn[256];
    __shared__ int   s_sl[8];
    __shared__ float s_m[64];
    __shared__ float s_rv[8];
    __shared__ float s_cs[512];
    __shared__ float s_css[64];
    __shared__ float s_eun[64];
    __shared__ float s_eu[64];
    __shared__ float s_w[64];
    __shared__ float s_loss[C_ * 8];
    __shared__ float s_red[4];
    __shared__ float s_inv, s_lth;
    __shared__ int   s_amin[8];
    __shared__ int   s_cidx[8];

    // ---- issue eu global loads EARLY (latency hides under staging+phase1) ----
    const int srow = tid >> 2, j4 = tid & 3;   // 4 lanes per s-row
    const float4* nrow = reinterpret_cast<const float4*>(nei_emb + (size_t)t * S_ * D_);
    float4 nv[16];
#pragma unroll
    for (int i = 0; i < 16; i++) nv[i] = nrow[srow * 64 + i * 4 + j4];

    // ---- stage ----
    float stav = sta_emb[t * D_ + tid];
    s_sta[tid] = stav;
    s_nl[tid]       = nei_loc[t * 512 + tid];
    s_nl[tid + 256] = nei_loc[t * 512 + tid + 256];
    s_rn[tid] = rand_numbers[t * 256 + tid];
    if (tid < 8) { s_sl[tid] = sta_loc[t * 8 + tid]; s_rv[tid] = rand_vals[t * 8 + tid]; }
    if (tid < 64) s_m[tid] = mask[t * 64 + tid];
    __syncthreads();

    // ---- phase 1: cos_sn, sta-norm partials, lth (exact: mask is 0/1) ----
    {
        s_cs[tid]       = cos_sim_i(s_sl[tid & 7], s_nl[tid]);
        s_cs[tid + 256] = cos_sim_i(s_sl[tid & 7], s_nl[tid + 256]);
        float sq = stav * stav;
#pragma unroll
        for (int off = 32; off; off >>= 1) sq += __shfl_xor(sq, off, 64);
        if (lane == 0) s_red[wave] = sq;
        if (wave == 1) {
            float mv = s_m[lane];
#pragma unroll
            for (int off = 32; off; off >>= 1) mv += __shfl_xor(mv, off, 64);
            if (lane == 0) s_lth = mv + 1e-12f;
        }
    }
    __syncthreads();

    // ---- phase 2: s_inv, css (exact any order), eu numerators ----
    if (tid == 0) s_inv = 1.0f / sqrtf(s_red[0] + s_red[1] + s_red[2] + s_red[3]);
    if (tid < 64) {
        float a = s_cs[tid * 8];
        for (int p = 1; p < 8; p++) a += s_cs[tid * 8 + p];
        s_css[tid] = a;
    }
    {
        const float4* st4 = reinterpret_cast<const float4*>(s_sta);
        float d0 = 0.f, n0 = 0.f;
#pragma unroll
        for (int i = 0; i < 16; i++) {
            float4 sv = st4[i * 4 + j4];
            float4 nn = nv[i];
            d0 = fmaf(nn.x, sv.x, d0); d0 = fmaf(nn.y, sv.y, d0);
            d0 = fmaf(nn.z, sv.z, d0); d0 = fmaf(nn.w, sv.w, d0);
            n0 = fmaf(nn.x, nn.x, n0); n0 = fmaf(nn.y, nn.y, n0);
            n0 = fmaf(nn.z, nn.z, n0); n0 = fmaf(nn.w, nn.w, n0);
        }
        d0 += __shfl_xor(d0, 1, 64); d0 += __shfl_xor(d0, 2, 64);
        n0 += __shfl_xor(n0, 1, 64); n0 += __shfl_xor(n0, 2, 64);
        if (j4 == 0) s_eun[srow] = d0 * (1.0f / sqrtf(n0));
    }
    __syncthreads();

    // ---- phase 3: build packed cb[s*8+p] = (code, g, eu, w) ----
#pragma unroll
    for (int q = tid; q < 512; q += 256) {
        int s = q >> 3;
        int nl = s_nl[q];
        int code = (nl < 0) ? (int)(0x80000000u | (unsigned)(-nl)) : nl;
        float g = s_css[s] - s_cs[q];          // exact (multiples of 1/16)
        float eu = s_eun[s] * s_inv;
        float w = fabsf(eu) * s_m[s];
        s_cb[q] = make_float4(__int_as_float(code), g, eu, w);
        if ((q & 7) == 0) { s_eu[s] = eu; s_w[s] = w; }
    }
    __syncthreads();

    // ---- phase 4: loss. One (c, c+33) pair per thread; c=32 on lanes 0..7 ----
    {
        const float lth = s_lth;
        const int c = tid >> 3, p = tid & 7;
        int v = cnc_val(c, s_sl[p], s_rn, p);
        unsigned avc  = (v < 0) ? (0x80000000u | (unsigned)(-v)) : (unsigned)v;
        unsigned flip = (v != 0) ? 0x80000000u : 0u;   // cos(-v,nl) = -cos(v,nl) unless v==0
        float acc1 = 0.f, acc2 = 0.f;
#pragma unroll 4
        for (int s = 0; s < 64; s++) {
            float4 cb = s_cb[s * 8 + p];
            unsigned y = avc ^ (unsigned)__float_as_int(cb.x);  // low31: abs^abs, top: sign product
            int x = (int)(y & 0x7fffffffu) + 1;
            float ccu = fmaf((float)__clz(x), 0.0625f, -1.0f);  // = 1 - e/16 (exact)
            unsigned ccb = __float_as_uint(ccu) ^ (y & 0x80000000u);
            float cc1 = __uint_as_float(ccb);
            float cc2 = __uint_as_float(ccb ^ flip);
            float d1 = fmaf(cb.y + cc1, 0.125f, -cb.z);  // exact product, 1 rounding = ref
            float d2 = fmaf(cb.y + cc2, 0.125f, -cb.z);
            acc1 = fmaf(d1 * d1, cb.w, acc1);
            acc2 = fmaf(d2 * d2, cb.w, acc2);
        }
        s_loss[c * 8 + p]        = acc1 / lth;
        s_loss[(c + 33) * 8 + p] = acc2 / lth;
        if (tid < 8) {   // c = 32: ct = css/8 (p-independent), serial ascending like others
            float a32 = 0.f;
            for (int s = 0; s < 64; s++) {
                float d = fmaf(s_css[s], 0.125f, -s_eu[s]);
                a32 = fmaf(d * d, s_w[s], a32);
            }
            s_loss[256 + tid] = a32 / lth;
        }
    }
    __syncthreads();

    // ---- phase 5: argmin over c per p (8 lanes per p, first-min tie-break) ----
    if (tid < 64) {
        const int p = tid >> 3, g = tid & 7;
        float bv = s_loss[g * 8 + p];
        int bi = g;
        for (int k = 1; k < 8; k++) {
            int c = g + 8 * k;
            float vv = s_loss[c * 8 + p];
            if (vv < bv) { bv = vv; bi = c; }
        }
        if (g == 0) {
            float vv = s_loss[512 + p];
            if (vv < bv) { bv = vv; bi = 64; }
        }
#pragma unroll
        for (int off = 1; off < 8; off <<= 1) {
            float ov = __shfl_xor(bv, off, 64);
            int   oi = __shfl_xor(bi, off, 64);
            if (ov < bv || (ov == bv && oi < bi)) { bv = ov; bi = oi; }
        }
        if (g == 0) s_amin[p] = bi;
    }
    __syncthreads();

    // ---- phase 6: selection (tiny, serial) ----
    if (tid == 0) {
        bool sel = t_rand[t] < 0.8f;
        float rv[8]; int cidx[8]; bool taken[8];
        for (int p = 0; p < 8; p++) { rv[p] = s_rv[p]; cidx[p] = 32; taken[p] = false; }
        for (int j = 0; j < 4; j++) {
            int bi = -1; float bvv = 0.f;
            for (int p = 0; p < 8; p++) {
                if (taken[p]) continue;
                if (bi < 0 || rv[p] < bvv) { bi = p; bvv = rv[p]; }  // strict <: stable
            }
            taken[bi] = true;
            cidx[bi] = sel ? s_amin[bi] : 32;
        }
        for (int p = 0; p < 8; p++) s_cidx[p] = cidx[p];
    }
    __syncthreads();

    // ---- phase 7: outputs ----
    if (tid < 8) {
        int c = s_cidx[tid];
        out_sel[t * 8 + tid] = (float)cnc_val(c, s_sl[tid], s_rn, tid);
    }
    if (tid == 64) {
        float a = 0.f;
        for (int p = 0; p < 8; p++) a += s_loss[s_cidx[p] * 8 + p];
        out_loss[t] = a * 0.125f;
    }
}

extern "C" void kernel_launch(void* const* d_in, const int* in_sizes, int n_in,
                              void* d_out, int out_size, void* d_ws, size_t ws_size,
                              hipStream_t stream) {
    const int*   sta_loc      = (const int*)d_in[0];
    const int*   nei_loc      = (const int*)d_in[1];
    const int*   rand_numbers = (const int*)d_in[2];
    const float* sta_emb      = (const float*)d_in[3];
    const float* nei_emb      = (const float*)d_in[4];
    const float* mask         = (const float*)d_in[5];
    const float* rand_vals    = (const float*)d_in[6];
    const float* t_rand       = (const float*)d_in[7];

    float* out_sel  = (float*)d_out;
    float* out_loss = out_sel + T_ * TP_;

    critigraph_kernel<<<T_, 256, 0, stream>>>(
        sta_loc, nei_loc, rand_numbers, sta_emb, nei_emb, mask,
        rand_vals, t_rand, out_sel, out_loss);
}

// Round 4
// 113.015 us; speedup vs baseline: 1.2061x; 1.0036x over previous
//
#include <hip/hip_runtime.h>
#include <math.h>

#define T_ 1024

__device__ __forceinline__ unsigned icode(int v) {
    return (v < 0) ? (0x80000000u | (unsigned)(-v)) : (unsigned)v;
}

// cos_sim on sign|abs codes; bit-exact vs reference (verified R1/R3, absmax 0)
__device__ __forceinline__ float cosc(unsigned ca, unsigned cb) {
    unsigned y = ca ^ cb;                       // low31: |a|^|b|, top: sign product
    int x = (int)(y & 0x7fffffffu) + 1;
    float m = fmaf((float)__clz(x), 0.0625f, -1.0f);   // 1 - e/16 (exact)
    return __uint_as_float(__float_as_uint(m) ^ (y & 0x80000000u));
}

__device__ __forceinline__ int cnc_val(int c, int sl, const int* rn, int p) {
    if (c == 32) return sl;
    int cc = (c < 32) ? c : (c - 33);
    int h = cc >> 1, k = cc & 1;
    int m = rn[h * 16 + k * 8 + p] & ((1 << h) - 1);
    int v = (sl ^ (1 << h)) ^ m;
    return (c < 32) ? v : -v;
}

__global__ __launch_bounds__(256, 4) void critigraph_kernel(
    const int* __restrict__ sta_loc,      // (T, 8)
    const int* __restrict__ nei_loc,      // (T, 64, 8)
    const int* __restrict__ rand_numbers, // (T, 16, 2, 8)
    const float* __restrict__ sta_emb,    // (T, 256)
    const float* __restrict__ nei_emb,    // (T, 64, 256)
    const float* __restrict__ mask,       // (T, 64)
    const float* __restrict__ rand_vals,  // (T, 8)
    const float* __restrict__ t_rand,     // (T,)
    float* __restrict__ out_sel,          // (T, 8)
    float* __restrict__ out_loss)         // (T,)
{
    const int t = blockIdx.x;
    const int tid = threadIdx.x;
    const int srow = tid >> 2, j4 = tid & 3;   // eu: 4 lanes per s-row
    const int c = tid >> 3, p = tid & 7;       // loss: unit (c, c+33) x p

    __shared__ __align__(16) float    s_sta[256];
    __shared__ __align__(16) unsigned s_nlc[512];   // sign|abs codes of nei_loc
    __shared__ __align__(16) int      s_rn[256];
    __shared__ __align__(8)  float2   s_cg[512];    // (code, css-cs) per (s,p)
    __shared__ __align__(8)  float2   s_ew[64];     // (eu, w) per s
    __shared__ float  s_css[64];
    __shared__ float  s_loss[520];
    __shared__ int    s_sl[8];
    __shared__ unsigned s_slc[8];
    __shared__ float  s_m[64];
    __shared__ float  s_rv[8];
    __shared__ float  s_lth;

    // ---- staging loads FIRST (vmcnt retires in issue order: these must not
    //      queue behind the 16 nei_emb loads) ----
    float stav = sta_emb[t * 256 + tid];
    int nl0 = nei_loc[t * 512 + tid];
    int nl1 = nei_loc[t * 512 + 256 + tid];
    int rnv = rand_numbers[t * 256 + tid];
    int slv = 0; float rvv = 0.f;
    if (tid < 8) { slv = sta_loc[t * 8 + tid]; rvv = rand_vals[t * 8 + tid]; }
    float mv = (tid < 64) ? mask[t * 64 + tid] : 0.f;
    float trv = t_rand[t];

    // ---- nei_emb loads AFTER: drain inside the dot loop ----
    const float4* nrow = reinterpret_cast<const float4*>(nei_emb + (size_t)t * 64 * 256);
    float4 nv[16];
#pragma unroll
    for (int i = 0; i < 16; i++) nv[i] = nrow[srow * 64 + i * 4 + j4];

    s_sta[tid] = stav;
    s_nlc[tid]       = icode(nl0);
    s_nlc[tid + 256] = icode(nl1);
    s_rn[tid] = rnv;
    if (tid < 8) { s_sl[tid] = slv; s_slc[tid] = icode(slv); s_rv[tid] = rvv; }
    if (tid < 64) s_m[tid] = mv;
    __syncthreads();   // sync1

    // ================= phase A (no internal barriers) =================
    // lth on wave 1 (mask is 0/1: sum exact any order)
    if ((tid >> 6) == 1) {
        float x = s_m[tid & 63];
#pragma unroll
        for (int off = 32; off; off >>= 1) x += __shfl_xor(x, off, 64);
        if ((tid & 63) == 0) s_lth = x + 1e-12f;
    }

    // int side: per thread, rows s0=tid>>3 and s0+32; css computed redundantly
    // (8 cos each, exact multiples of 1/16 -> order-independent)
    {
        unsigned slc[8];
#pragma unroll
        for (int i = 0; i < 8; i++) slc[i] = s_slc[i];
        const uint4* nl4 = reinterpret_cast<const uint4*>(s_nlc);
        const int s0 = tid >> 3;
#pragma unroll
        for (int half = 0; half < 2; half++) {
            int s = s0 + half * 32;
            uint4 ra = nl4[s * 2], rb = nl4[s * 2 + 1];
            unsigned nn[8] = {ra.x, ra.y, ra.z, ra.w, rb.x, rb.y, rb.z, rb.w};
            float css = 0.f, csm[8];
#pragma unroll
            for (int i = 0; i < 8; i++) { csm[i] = cosc(slc[i], nn[i]); css += csm[i]; }
            if (p == 0) s_css[s] = css;
            s_cg[s * 8 + p] = make_float2(__uint_as_float(nn[p]), css - csm[p]);
        }
    }

    // eu side: dot + nei-norm + sta-norm in one pass (4-lane group holds the
    // full 256-dim sta vector across its 64 st4 reads)
    {
        const float4* st4 = reinterpret_cast<const float4*>(s_sta);
        float d0 = 0.f, n0 = 0.f, a0 = 0.f;
#pragma unroll
        for (int i = 0; i < 16; i++) {
            float4 sv = st4[i * 4 + j4];
            float4 nn = nv[i];
            d0 = fmaf(nn.x, sv.x, d0); d0 = fmaf(nn.y, sv.y, d0);
            d0 = fmaf(nn.z, sv.z, d0); d0 = fmaf(nn.w, sv.w, d0);
            n0 = fmaf(nn.x, nn.x, n0); n0 = fmaf(nn.y, nn.y, n0);
            n0 = fmaf(nn.z, nn.z, n0); n0 = fmaf(nn.w, nn.w, n0);
            a0 = fmaf(sv.x, sv.x, a0); a0 = fmaf(sv.y, sv.y, a0);
            a0 = fmaf(sv.z, sv.z, a0); a0 = fmaf(sv.w, sv.w, a0);
        }
        d0 += __shfl_xor(d0, 1, 64); d0 += __shfl_xor(d0, 2, 64);
        n0 += __shfl_xor(n0, 1, 64); n0 += __shfl_xor(n0, 2, 64);
        a0 += __shfl_xor(a0, 1, 64); a0 += __shfl_xor(a0, 2, 64);
        if (j4 == 0) {
            float eun = d0 * (1.0f / sqrtf(n0));     // same op order as R3 (passed)
            float eu  = eun * (1.0f / sqrtf(a0));
            float w   = fabsf(eu) * s_m[srow];
            s_ew[srow] = make_float2(eu, w);
        }
    }

    // candidate precompute (only needs staged ints)
    int vcn = cnc_val(c, s_sl[p], s_rn, p);
    unsigned avc  = icode(vcn);
    unsigned flip = (vcn != 0) ? 0x80000000u : 0u;   // cos(-v,.) = -cos(v,.) unless v==0
    __syncthreads();   // sync2

    // ================= loss =================
    {
        float acc1 = 0.f, acc2 = 0.f;
#pragma unroll 4
        for (int s = 0; s < 64; s++) {
            float2 cg = s_cg[s * 8 + p];
            float2 ew = s_ew[s];                     // wave-uniform broadcast
            unsigned y = avc ^ __float_as_uint(cg.x);
            int x = (int)(y & 0x7fffffffu) + 1;
            float m1 = fmaf((float)__clz(x), 0.0625f, -1.0f);
            unsigned cb = __float_as_uint(m1) ^ (y & 0x80000000u);
            float cc1 = __uint_as_float(cb);
            float cc2 = __uint_as_float(cb ^ flip);
            float d1 = fmaf(cg.y + cc1, 0.125f, -ew.x);  // exact numerator, 1 rounding
            float d2 = fmaf(cg.y + cc2, 0.125f, -ew.x);
            acc1 = fmaf(d1 * d1, ew.y, acc1);
            acc2 = fmaf(d2 * d2, ew.y, acc2);
        }
        float lth = s_lth;
        s_loss[c * 8 + p]        = acc1 / lth;
        s_loss[(c + 33) * 8 + p] = acc2 / lth;
        if (tid < 8) {   // c=32: ct = css/8 (p-independent), serial ascending
            float a32 = 0.f;
            for (int s = 0; s < 64; s++) {
                float2 ew = s_ew[s];
                float d = fmaf(s_css[s], 0.125f, -ew.x);
                a32 = fmaf(d * d, ew.y, a32);
            }
            s_loss[256 + tid] = a32 / lth;
        }
    }
    __syncthreads();   // sync3

    // ================= wave-0 epilogue (argmin + rank-select + outputs) =====
    if (tid < 64) {
        const int pp = tid >> 3, g = tid & 7;
        float bv = s_loss[g * 8 + pp];
        int bi = g;
#pragma unroll
        for (int k = 1; k < 8; k++) {            // ascending c: first-min tie-break
            float vv = s_loss[(g + 8 * k) * 8 + pp];
            if (vv < bv) { bv = vv; bi = g + 8 * k; }
        }
        if (g == 0) {
            float vv = s_loss[512 + pp];         // c = 64
            if (vv < bv) { bv = vv; bi = 64; }
        }
#pragma unroll
        for (int off = 1; off < 8; off <<= 1) {  // lexicographic butterfly
            float ov = __shfl_xor(bv, off, 64);
            int   oi = __shfl_xor(bi, off, 64);
            if (ov < bv || (ov == bv && oi < bi)) { bv = ov; bi = oi; }
        }
        // stable-argsort rank of pp among rand_vals; top-4 <=> rank < 4
        bool sel = trv < 0.8f;
        float rme = s_rv[pp];
        int rank = 0;
#pragma unroll
        for (int p2 = 0; p2 < 8; p2++) {
            float ro = s_rv[p2];
            rank += (ro < rme || (ro == rme && p2 < pp)) ? 1 : 0;
        }
        int cidx = (rank < 4 && sel) ? bi : 32;
        if (g == 0)
            out_sel[t * 8 + pp] = (float)cnc_val(cidx, s_sl[pp], s_rn, pp);
        // real_loss: gather cidx via shuffle, serial ascending sum on lane 0
        float a = 0.f;
#pragma unroll
        for (int p2 = 0; p2 < 8; p2++) {
            int cx = __shfl(cidx, p2 * 8, 64);
            a += s_loss[cx * 8 + p2];
        }
        if (tid == 0) out_loss[t] = a * 0.125f;
    }
}

extern "C" void kernel_launch(void* const* d_in, const int* in_sizes, int n_in,
                              void* d_out, int out_size, void* d_ws, size_t ws_size,
                              hipStream_t stream) {
    const int*   sta_loc      = (const int*)d_in[0];
    const int*   nei_loc      = (const int*)d_in[1];
    const int*   rand_numbers = (const int*)d_in[2];
    const float* sta_emb      = (const float*)d_in[3];
    const float* nei_emb      = (const float*)d_in[4];
    const float* mask         = (const float*)d_in[5];
    const float* rand_vals    = (const float*)d_in[6];
    const float* t_rand       = (const float*)d_in[7];

    float* out_sel  = (float*)d_out;
    float* out_loss = out_sel + T_ * 8;

    critigraph_kernel<<<T_, 256, 0, stream>>>(
        sta_loc, nei_loc, rand_numbers, sta_emb, nei_emb, mask,
        rand_vals, t_rand, out_sel, out_loss);
}